// Round 1
// baseline (832.199 us; speedup 1.0000x reference)
//
#include <hip/hip_runtime.h>
#include <hip/hip_bf16.h>

#define B_     16
#define CIN_   512
#define COUT_  512
#define RES_   64
#define WDIM_  512
#define LRELU_A 0.2f
#define GAIN_  1.4142135623730951f

typedef __attribute__((ext_vector_type(8)))  __bf16 bf16x8;
typedef __attribute__((ext_vector_type(16))) float  f32x16;

__device__ __forceinline__ unsigned short f2bf(float f) {
    union { float f; unsigned int u; } v; v.f = f;
    unsigned int u = v.u;
    return (unsigned short)((u + 0x7FFFu + ((u >> 16) & 1u)) >> 16);  // RNE
}

// ---------------- K1: styles = w @ (affine_w^T / sqrt(512)) + affine_b ----------------
__global__ void styles_k(const float* __restrict__ w, const float* __restrict__ aw,
                         const float* __restrict__ ab, float* __restrict__ styles) {
    int idx = blockIdx.x * 256 + threadIdx.x;      // 8192 = b*512 + ci
    int b = idx >> 9, ci = idx & 511;
    const float4* wp = (const float4*)(w + b * WDIM_);
    const float4* ap = (const float4*)(aw + (size_t)ci * WDIM_);
    float acc = 0.f;
    #pragma unroll 4
    for (int k = 0; k < WDIM_ / 4; ++k) {
        float4 a = ap[k], q = wp[k];
        acc += a.x * q.x + a.y * q.y + a.z * q.z + a.w * q.w;
    }
    styles[idx] = acc * 0.04419417382415922f + ab[ci];   // 1/sqrt(512)
}

// ---------------- K2: wt[tap][co][ci] (bf16) and wsq[co][ci] = sum_tap w^2 ----------------
__global__ void wprep_k(const float* __restrict__ weight, unsigned short* __restrict__ wt,
                        float* __restrict__ wsq) {
    int idx = blockIdx.x * 256 + threadIdx.x;      // 262144 = co*512 + ci
    const float* wp = weight + (size_t)idx * 9;
    float s = 0.f;
    #pragma unroll
    for (int t = 0; t < 9; ++t) {
        float f = wp[t];
        s += f * f;
        wt[(size_t)t * (COUT_ * CIN_) + idx] = f2bf(f);
    }
    wsq[idx] = s;
}

// ---------------- K3: demod[b][co] = rsqrt(sum_ci wsq[co][ci]*styles[b][ci]^2 + 1e-8) ----
__global__ void demod_k(const float* __restrict__ styles, const float* __restrict__ wsq,
                        float* __restrict__ demod) {
    int idx = blockIdx.x * 256 + threadIdx.x;      // 8192 = b*512 + co
    int b = idx >> 9, co = idx & 511;
    const float4* wr = (const float4*)(wsq + (size_t)co * CIN_);
    const float4* sr = (const float4*)(styles + (size_t)b * CIN_);
    float acc = 0.f;
    #pragma unroll 4
    for (int ci = 0; ci < CIN_ / 4; ++ci) {
        float4 q = wr[ci], s = sr[ci];
        acc += q.x * s.x * s.x + q.y * s.y * s.y + q.z * s.z * s.z + q.w * s.w * s.w;
    }
    demod[idx] = rsqrtf(acc + 1e-8f);
}

// ---------------- K4: main conv. MT=512 co x NT=128 px (2 rows), CK=16, 8 waves ----------
#define CK 16
#define LDSPITCH 24                 // shorts per (row,col) cell: 16 used + pad, 48B (16B-aligned)
#define LDSROW  (66 * LDSPITCH)
#define LDSBUF  (4 * LDSROW)        // 4 input rows

__global__ __launch_bounds__(512, 2) void conv_k(
    const float* __restrict__ x, const float* __restrict__ styles,
    const unsigned short* __restrict__ wt, const float* __restrict__ demod,
    const float* __restrict__ bias, const float* __restrict__ noise,
    const float* __restrict__ nsp, float* __restrict__ out)
{
    __shared__ unsigned short xs[2 * LDSBUF];

    const int tid    = threadIdx.x;
    const int lane   = tid & 63;
    const int wid    = tid >> 6;          // 0..7
    const int wave_m = wid & 3;           // 4 m-groups of 128 co
    const int wave_n = wid >> 2;          // output row within pair
    const int blk    = blockIdx.x;        // 512 = 32 hb * 16 b
    const int hb     = blk & 31;
    const int b      = blk >> 5;
    const int h0     = hb * 2;
    const int l31    = lane & 31;
    const int kg     = lane >> 5;         // k-group (0/1)

    // zero halo cols (col 0 and 65 = w=-1 and w=64), both buffers, rows 0..3, k 0..15
    if (tid < 128) {
        int kp = tid & 7, c = (tid >> 3) & 1, r = (tid >> 4) & 3, bf = tid >> 6;
        *(unsigned int*)&xs[bf * LDSBUF + (r * 66 + c * 65) * LDSPITCH + kp * 2] = 0u;
    }

    const int s_c = tid & 63;             // col
    const int s_p = tid >> 6;             // 0..7 (wave-uniform -> scalar styles loads)
    float sa0[4], sa1[4];

    auto stage_load = [&](int cc) {
        #pragma unroll
        for (int it = 0; it < 4; ++it) {
            int p = it * 8 + s_p;
            int r = p >> 3, cp = p & 7;
            int ci = cc * CK + cp * 2;
            int in_row = h0 - 1 + r;
            bool v = (in_row >= 0) && (in_row < RES_);
            const float* xp = x + (((size_t)(b * CIN_ + ci) * RES_ + (v ? in_row : 0)) * RES_) + s_c;
            float a0 = v ? xp[0] : 0.f;
            float a1 = v ? xp[RES_ * RES_] : 0.f;
            sa0[it] = a0 * styles[b * CIN_ + ci];
            sa1[it] = a1 * styles[b * CIN_ + ci + 1];
        }
    };
    auto stage_write = [&](int buf) {
        #pragma unroll
        for (int it = 0; it < 4; ++it) {
            int p = it * 8 + s_p;
            int r = p >> 3, cp = p & 7;
            unsigned int u = (unsigned int)f2bf(sa0[it]) | ((unsigned int)f2bf(sa1[it]) << 16);
            *(unsigned int*)&xs[buf * LDSBUF + (r * 66 + s_c + 1) * LDSPITCH + cp * 2] = u;
        }
    };

    f32x16 acc[4][2];
    #pragma unroll
    for (int mt = 0; mt < 4; ++mt)
        #pragma unroll
        for (int nt = 0; nt < 2; ++nt)
            #pragma unroll
            for (int j = 0; j < 16; ++j) acc[mt][nt][j] = 0.f;

    // per-thread W base: row = wave_m*128 + l31 (co), k offset = kg*8 within chunk
    const unsigned short* wbase = wt + (size_t)(wave_m * 128 + l31) * CIN_ + kg * 8;

    stage_load(0);
    stage_write(0);
    __syncthreads();

    for (int cc = 0; cc < CIN_ / CK; ++cc) {
        if (cc + 1 < CIN_ / CK) stage_load(cc + 1);      // loads in flight across MFMA block
        const int buf = cc & 1;
        const unsigned short* wcc = wbase + cc * CK;
        #pragma unroll
        for (int tap = 0; tap < 9; ++tap) {
            const int dy = tap / 3, dx = tap % 3;        // compile-time under unroll
            bf16x8 af[4];
            #pragma unroll
            for (int mt = 0; mt < 4; ++mt)
                af[mt] = *(const bf16x8*)(wcc + (size_t)tap * (COUT_ * CIN_) + mt * 32 * CIN_);
            bf16x8 bfr[2];
            #pragma unroll
            for (int nt = 0; nt < 2; ++nt) {
                int r   = wave_n + dy;                   // LDS row (input row h0-1+r)
                int col = nt * 32 + l31 + dx;            // LDS col (w + dx), halo at 0/65
                bfr[nt] = *(const bf16x8*)&xs[buf * LDSBUF + (r * 66 + col) * LDSPITCH + kg * 8];
            }
            #pragma unroll
            for (int mt = 0; mt < 4; ++mt)
                #pragma unroll
                for (int nt = 0; nt < 2; ++nt)
                    acc[mt][nt] = __builtin_amdgcn_mfma_f32_32x32x16_bf16(
                        af[mt], bfr[nt], acc[mt][nt], 0, 0, 0);
        }
        if (cc + 1 < CIN_ / CK) stage_write((cc + 1) & 1);
        __syncthreads();
    }

    // epilogue: demod, noise, bias, lrelu*gain
    const float nsv  = nsp[0];
    const int   orow = h0 + wave_n;
    float nz[2];
    nz[0] = noise[orow * RES_ + l31] * nsv;
    nz[1] = noise[orow * RES_ + 32 + l31] * nsv;
    #pragma unroll
    for (int mt = 0; mt < 4; ++mt) {
        #pragma unroll
        for (int nt = 0; nt < 2; ++nt) {
            #pragma unroll
            for (int j = 0; j < 16; ++j) {
                // C/D layout (verified m74/m101): col = lane&31, row = (j&3) + 8*(j>>2) + 4*kg
                int co = wave_m * 128 + mt * 32 + (j & 3) + 8 * (j >> 2) + 4 * kg;
                float v = acc[mt][nt][j] * demod[b * COUT_ + co] + nz[nt] + bias[co];
                v = (v >= 0.f ? v : LRELU_A * v) * GAIN_;
                out[((size_t)(b * COUT_ + co) * RES_ + orow) * RES_ + nt * 32 + l31] = v;
            }
        }
    }
}

extern "C" void kernel_launch(void* const* d_in, const int* in_sizes, int n_in,
                              void* d_out, int out_size, void* d_ws, size_t ws_size,
                              hipStream_t stream) {
    const float* x    = (const float*)d_in[0];
    const float* w    = (const float*)d_in[1];
    const float* wgt  = (const float*)d_in[2];
    const float* bias = (const float*)d_in[3];
    const float* aw   = (const float*)d_in[4];
    const float* ab   = (const float*)d_in[5];
    const float* noi  = (const float*)d_in[6];
    const float* ns   = (const float*)d_in[7];
    float* out = (float*)d_out;

    char* ws = (char*)d_ws;
    float* styles        = (float*)(ws);                       // 8192 f32
    float* demod         = (float*)(ws + 32768);               // 8192 f32
    float* wsq           = (float*)(ws + 65536);               // 262144 f32
    unsigned short* wt   = (unsigned short*)(ws + 65536 + 1048576); // 9*512*512 bf16

    hipLaunchKernelGGL(styles_k, dim3(32),   dim3(256), 0, stream, w, aw, ab, styles);
    hipLaunchKernelGGL(wprep_k,  dim3(1024), dim3(256), 0, stream, wgt, wt, wsq);
    hipLaunchKernelGGL(demod_k,  dim3(32),   dim3(256), 0, stream, styles, wsq, demod);
    hipLaunchKernelGGL(conv_k,   dim3(512),  dim3(512), 0, stream,
                       x, styles, wt, demod, bias, noi, ns, out);
}

// Round 3
// 523.750 us; speedup vs baseline: 1.5889x; 1.5889x over previous
//
#include <hip/hip_runtime.h>
#include <hip/hip_bf16.h>

#define B_     16
#define CIN_   512
#define COUT_  512
#define RES_   64
#define WDIM_  512
#define LRELU_A 0.2f
#define GAIN_  1.4142135623730951f

typedef __attribute__((ext_vector_type(8)))  __bf16 bf16x8;
typedef __attribute__((ext_vector_type(16))) float  f32x16;
typedef __attribute__((ext_vector_type(4)))  int    int4v;

__device__ __forceinline__ unsigned short f2bf(float f) {
    union { float f; unsigned int u; } v; v.f = f;
    unsigned int u = v.u;
    return (unsigned short)((u + 0x7FFFu + ((u >> 16) & 1u)) >> 16);  // RNE
}

// async global->LDS, 16B per lane; LDS dest = wave-uniform base + lane*16
__device__ __forceinline__ void gl_lds16(const void* g, void* l) {
    __builtin_amdgcn_global_load_lds(
        (const __attribute__((address_space(1))) unsigned int*)g,
        (__attribute__((address_space(3))) unsigned int*)l, 16, 0, 0);
}

// ---------------- K0: zero halo rows (padded rows 0 and 65 of each b) -------------------
__global__ void zero_k(unsigned short* __restrict__ xs) {
    int idx = blockIdx.x * 256 + threadIdx.x;          // 131072 chunks of 16B
    int b = idx >> 13, side = (idx >> 12) & 1, off = idx & 4095;
    int4v z = {0, 0, 0, 0};
    *(int4v*)((char*)xs + ((size_t)(b * 66 + side * 65) * 4096 + off) * 16) = z;
}

// ---------------- K1: styles = w @ (affine_w^T / sqrt(512)) + affine_b ----------------
__global__ void styles_k(const float* __restrict__ w, const float* __restrict__ aw,
                         const float* __restrict__ ab, float* __restrict__ styles) {
    int idx = blockIdx.x * 256 + threadIdx.x;      // 8192 = b*512 + ci
    int b = idx >> 9, ci = idx & 511;
    const float4* wp = (const float4*)(w + b * WDIM_);
    const float4* ap = (const float4*)(aw + (size_t)ci * WDIM_);
    float acc = 0.f;
    #pragma unroll 4
    for (int k = 0; k < WDIM_ / 4; ++k) {
        float4 a = ap[k], q = wp[k];
        acc += a.x * q.x + a.y * q.y + a.z * q.z + a.w * q.w;
    }
    styles[idx] = acc * 0.04419417382415922f + ab[ci];   // 1/sqrt(512)
}

// ---------------- K2: wt_pack[cc][tap][co][ci16] bf16, wsq[co][ci] = sum_tap w^2 --------
__global__ void wprep_k(const float* __restrict__ weight, unsigned short* __restrict__ wt,
                        float* __restrict__ wsq) {
    int idx = blockIdx.x * 256 + threadIdx.x;      // 262144 = co*512 + ci
    int co = idx >> 9, ci = idx & 511;
    const float* wp = weight + (size_t)idx * 9;
    float s = 0.f;
    #pragma unroll
    for (int t = 0; t < 9; ++t) {
        float f = wp[t];
        s += f * f;
        // [cc=ci>>4][tap][co 0..511][ci&15]
        wt[(((size_t)(ci >> 4) * 9 + t) * 512 + co) * 16 + (ci & 15)] = f2bf(f);
    }
    wsq[idx] = s;
}

// ---------------- K3: demod[b][co] = rsqrt(sum_ci wsq[co][ci]*styles[b][ci]^2 + 1e-8) ----
__global__ void demod_k(const float* __restrict__ styles, const float* __restrict__ wsq,
                        float* __restrict__ demod) {
    int idx = blockIdx.x * 256 + threadIdx.x;      // 8192 = b*512 + co
    int b = idx >> 9, co = idx & 511;
    const float4* wr = (const float4*)(wsq + (size_t)co * CIN_);
    const float4* sr = (const float4*)(styles + (size_t)b * CIN_);
    float acc = 0.f;
    #pragma unroll 4
    for (int ci = 0; ci < CIN_ / 4; ++ci) {
        float4 q = wr[ci], s = sr[ci];
        acc += q.x * s.x * s.x + q.y * s.y * s.y + q.z * s.z * s.z + q.w * s.w * s.w;
    }
    demod[idx] = rsqrtf(acc + 1e-8f);
}

// ------- K4: xs[b][h+1][cc][w][ci16] = bf16(x[b][ci][h][w] * styles[b][ci]) -------------
__global__ void xprep_k(const float* __restrict__ x, const float* __restrict__ styles,
                        unsigned short* __restrict__ xs) {
    __shared__ float tile[64][65];
    int bid = blockIdx.x;                  // 8192 = b*512 + h*8 + ct
    int ct = bid & 7, h = (bid >> 3) & 63, b = bid >> 9;
    int tw = threadIdx.x & 63;
    int tr = threadIdx.x >> 6;             // 0..3
    const float* xp = x + (((size_t)(b * CIN_ + ct * 64) * RES_ + h) * RES_);
    #pragma unroll
    for (int it = 0; it < 16; ++it) {
        int ci = tr + it * 4;
        tile[ci][tw] = xp[(size_t)ci * (RES_ * RES_) + tw];   // coalesced over w
    }
    __syncthreads();
    const float sv = styles[b * CIN_ + ct * 64 + tw];
    // row base: [b][h+1] has 32 cc * 64 w * 16 = 32768 shorts
    unsigned short* xo = xs + (size_t)(b * 66 + h + 1) * 32768
                            + ((size_t)(ct * 4 + (tw >> 4))) * 1024 + (tw & 15);
    #pragma unroll
    for (int it = 0; it < 16; ++it) {
        int w = tr + it * 4;
        xo[w * 16] = f2bf(tile[tw][w] * sv);
    }
}

// ---------------- K5: main conv. block: 128 co x 512 px (8 rows), CK=16 ------------------
#define WBUF 36864                // 9 taps * 128 co * 32B
#define XBUF 21120                // 10 rows * 66 sites * 32B
#define LDS_TOTAL (2*WBUF + 2*XBUF)   // 115968

__global__ __launch_bounds__(512, 2) void conv_k(
    const unsigned short* __restrict__ xs, const unsigned short* __restrict__ wt,
    const float* __restrict__ demod, const float* __restrict__ bias,
    const float* __restrict__ noise, const float* __restrict__ nsp,
    float* __restrict__ out)
{
    extern __shared__ char lds[];
    char* Wl = lds;                    // [2][WBUF]
    char* Xl = lds + 2 * WBUF;         // [2][XBUF]

    const int tid  = threadIdx.x;
    const int lane = tid & 63;
    const int wid  = tid >> 6;         // 0..7 = output row within block
    const int l31  = lane & 31;
    const int kg   = lane >> 5;

    // XCD swizzle: 512 blocks; blocks on one XCD share the same W co-panel
    const int lb = ((blockIdx.x & 7) << 6) | (blockIdx.x >> 3);
    const int m  = lb >> 7;            // 0..3 co-panel
    const int pt = lb & 127;
    const int b  = pt >> 3;
    const int h0 = (pt & 7) * 8;

    // zero the column-halo sites (site 0 and 65 of each row, both buffers)
    if (tid < 80) {
        int buf = tid / 40, rem = tid % 40, r = rem >> 2, k = rem & 3;
        int chunk = r * 132 + (k < 2 ? k : 128 + k);
        int4v z = {0, 0, 0, 0};
        *(int4v*)(Xl + buf * XBUF + chunk * 16) = z;
    }

    const char* wsrc = (const char*)wt + (size_t)m * (128 * 32);
    auto stageW = [&](int cc, int buf) {
        const char* s0 = wsrc + (size_t)cc * (9 * 512 * 32);
        char* d0 = Wl + buf * WBUF;
        #pragma unroll
        for (int k = 0; k < 5; ++k) {
            if (k < 4 || wid < 4) {                    // wave-uniform guard (2304 chunks)
                const int c0 = k * 512 + wid * 64;
                const int c  = c0 + lane;
                gl_lds16(s0 + (size_t)(c >> 8) * 16384 + (c & 255) * 16, d0 + c0 * 16);
            }
        }
    };
    const char* xsrc = (const char*)xs + (size_t)(b * 66 + h0) * 65536;
    auto stageX = [&](int cc, int buf) {
        const char* s0 = xsrc + cc * 2048;             // [row][cc][w][ci16]
        char* d0 = Xl + buf * XBUF;
        #pragma unroll
        for (int k = 0; k < 3; ++k) {
            if (k < 2 || wid < 4) {                    // 1280 chunks
                const int c0 = k * 512 + wid * 64;
                const int c  = c0 + lane;
                const int r  = c0 >> 7;                // row, uniform within wave
                gl_lds16(s0 + (size_t)r * 65536 + (c & 127) * 16,
                         d0 + r * 2112 + ((c0 & 127) + 2) * 16);
            }
        }
    };

    f32x16 acc[4][2];
    #pragma unroll
    for (int mt = 0; mt < 4; ++mt)
        #pragma unroll
        for (int nt = 0; nt < 2; ++nt)
            #pragma unroll
            for (int j = 0; j < 16; ++j) acc[mt][nt][j] = 0.f;

    stageW(0, 0);
    stageX(0, 0);
    __syncthreads();

    int buf = 0;
    for (int cc = 0; cc < 32; ++cc) {
        if (cc < 31) { stageW(cc + 1, buf ^ 1); stageX(cc + 1, buf ^ 1); }
        const char* Wb = Wl + buf * WBUF;
        const char* Xb = Xl + buf * XBUF;
        #pragma unroll
        for (int t = 0; t < 9; ++t) {
            const int dy = t / 3, dx = t % 3;          // compile-time under unroll
            bf16x8 af[4], bv[2];
            #pragma unroll
            for (int mt = 0; mt < 4; ++mt)
                af[mt] = *(const bf16x8*)(Wb + ((t * 128 + mt * 32 + l31) << 5) + (kg << 4));
            #pragma unroll
            for (int nt = 0; nt < 2; ++nt) {
                int site = nt * 32 + l31 + dx;         // 0..65, halo pre-zeroed
                bv[nt] = *(const bf16x8*)(Xb + (wid + dy) * 2112 + site * 32 + (kg << 4));
            }
            #pragma unroll
            for (int mt = 0; mt < 4; ++mt)
                #pragma unroll
                for (int nt = 0; nt < 2; ++nt)
                    acc[mt][nt] = __builtin_amdgcn_mfma_f32_32x32x16_bf16(
                        af[mt], bv[nt], acc[mt][nt], 0, 0, 0);
        }
        __syncthreads();
        buf ^= 1;
    }

    // epilogue: demod, noise, bias, lrelu*gain
    const float nsv = nsp[0];
    const int h = h0 + wid;
    const float* dm = demod + b * COUT_ + m * 128;
    float nz[2];
    nz[0] = noise[h * 64 + l31] * nsv;
    nz[1] = noise[h * 64 + 32 + l31] * nsv;
    #pragma unroll
    for (int mt = 0; mt < 4; ++mt) {
        #pragma unroll
        for (int j = 0; j < 16; ++j) {
            // C/D layout (verified m74/m101): col = lane&31, row = (j&3)+8*(j>>2)+4*kg
            int row = (j & 3) + 8 * (j >> 2) + 4 * kg;
            int co  = mt * 32 + row;
            float d  = dm[co];
            float bs = bias[m * 128 + co];
            #pragma unroll
            for (int nt = 0; nt < 2; ++nt) {
                float v = acc[mt][nt][j] * d + nz[nt] + bs;
                v = (v >= 0.f ? v : LRELU_A * v) * GAIN_;
                out[((size_t)(b * COUT_ + m * 128 + co) * RES_ + h) * RES_ + nt * 32 + l31] = v;
            }
        }
    }
}

extern "C" void kernel_launch(void* const* d_in, const int* in_sizes, int n_in,
                              void* d_out, int out_size, void* d_ws, size_t ws_size,
                              hipStream_t stream) {
    const float* x    = (const float*)d_in[0];
    const float* w    = (const float*)d_in[1];
    const float* wgt  = (const float*)d_in[2];
    const float* bias = (const float*)d_in[3];
    const float* aw   = (const float*)d_in[4];
    const float* ab   = (const float*)d_in[5];
    const float* noi  = (const float*)d_in[6];
    const float* ns   = (const float*)d_in[7];
    float* out = (float*)d_out;

    char* ws = (char*)d_ws;
    float* styles        = (float*)(ws);                        // 32 KB
    float* demod         = (float*)(ws + 32768);                // 32 KB
    float* wsq           = (float*)(ws + 65536);                // 1 MB
    unsigned short* wt   = (unsigned short*)(ws + 1114112);     // 4.72 MB  [cc][tap][co][ci16]
    unsigned short* xs   = (unsigned short*)(ws + 6291456);     // 69.2 MB  [b][66][cc][w][ci16]

    hipLaunchKernelGGL(zero_k,   dim3(512),  dim3(256), 0, stream, xs);
    hipLaunchKernelGGL(styles_k, dim3(32),   dim3(256), 0, stream, w, aw, ab, styles);
    hipLaunchKernelGGL(wprep_k,  dim3(1024), dim3(256), 0, stream, wgt, wt, wsq);
    hipLaunchKernelGGL(xprep_k,  dim3(8192), dim3(256), 0, stream, x, styles, xs);
    hipLaunchKernelGGL(demod_k,  dim3(32),   dim3(256), 0, stream, styles, wsq, demod);

    hipFuncSetAttribute((const void*)conv_k, hipFuncAttributeMaxDynamicSharedMemorySize, LDS_TOTAL);
    hipLaunchKernelGGL(conv_k, dim3(512), dim3(512), LDS_TOTAL, stream,
                       xs, wt, demod, bias, noi, ns, out);
}